// Round 3
// baseline (3613.924 us; speedup 1.0000x reference)
//
#include <hip/hip_runtime.h>
#include <hip/hip_bf16.h>

#define B_ 2
#define S_ 2048
#define D_ 4096
#define NH_ 32
#define NKV_ 8
#define HD_ 128
#define NREP_ 4

typedef unsigned short u16;
typedef __attribute__((ext_vector_type(8))) short short8;
typedef __attribute__((ext_vector_type(4))) float f32x4;

__device__ inline float bf2f(u16 u) {
    union { unsigned u; float f; } v; v.u = ((unsigned)u) << 16; return v.f;
}
__device__ inline u16 f2bf(float f) {
    union { float f; unsigned u; } v; v.f = f;
    unsigned r = v.u + 0x7fffu + ((v.u >> 16) & 1u);
    return (u16)(r >> 16);
}

// ---------------- transpose (bf16 -> bf16): in [R][C] -> out [C][R] --------
__global__ __launch_bounds__(256) void transpose_k(const u16* __restrict__ in,
                                                   u16* __restrict__ out,
                                                   int R, int C) {
    __shared__ u16 tile[64][65];
    int bx = blockIdx.x * 64;   // col base in input
    int by = blockIdx.y * 64;   // row base in input
    int tx = threadIdx.x;       // 0..63
    int ty = threadIdx.y;       // 0..3
    for (int i = ty; i < 64; i += 4)
        tile[i][tx] = in[(size_t)(by + i) * C + bx + tx];
    __syncthreads();
    for (int i = ty; i < 64; i += 4)
        out[(size_t)(bx + i) * R + by + tx] = tile[tx][i];
}

// ---------------- GEMM: C[M][N] = A[M][K] * B[K][N] ------------------------
// A: f32 (A_F32=1) or bf16 (A_F32=0). B: f32 weights, transposed+converted to
// bf16 during LDS staging. C: f32 (OUT_F32=1) or bf16. MFMA bf16, f32 acc.
template <int A_F32, int OUT_F32>
__global__ __launch_bounds__(256) void gemm_nt(const void* __restrict__ Av,
                                               const float* __restrict__ Bf,
                                               void* __restrict__ Cv,
                                               int M, int N, int K) {
    __shared__ __align__(16) u16 As[128 * 32];   // [m][k]
    __shared__ __align__(16) u16 Bs[128 * 32];   // [n][k]  (transposed in staging)
    int tid = threadIdx.x;
    int w = tid >> 6, lane = tid & 63;
    int ln = lane & 15, qd = lane >> 4;
    int wr = w >> 1, wc = w & 1;
    int m0 = blockIdx.y * 128, n0 = blockIdx.x * 128;

    f32x4 acc[4][4];
#pragma unroll
    for (int i = 0; i < 4; ++i)
#pragma unroll
        for (int j = 0; j < 4; ++j)
            acc[i][j] = f32x4{0.f, 0.f, 0.f, 0.f};

    for (int k0 = 0; k0 < K; k0 += 32) {
        // ---- stage A tile [128 m][32 k] ----
        if (A_F32) {
            const float* A = (const float*)Av;
#pragma unroll
            for (int it = 0; it < 2; ++it) {
                int idx = (it * 256 + tid) * 8;       // 4096 elems
                int row = idx >> 5, kk = idx & 31;
                const float* src = &A[(size_t)(m0 + row) * K + k0 + kk];
                float4 v0 = *(const float4*)src;
                float4 v1 = *(const float4*)(src + 4);
                u16 tmp[8] = {f2bf(v0.x), f2bf(v0.y), f2bf(v0.z), f2bf(v0.w),
                              f2bf(v1.x), f2bf(v1.y), f2bf(v1.z), f2bf(v1.w)};
                *(int4*)&As[row * 32 + kk] = *(const int4*)tmp;
            }
        } else {
            const u16* A = (const u16*)Av;
#pragma unroll
            for (int it = 0; it < 2; ++it) {
                int idx = (it * 256 + tid) * 8;
                int row = idx >> 5, kk = idx & 31;
                *(int4*)&As[row * 32 + kk] =
                    *(const int4*)&A[(size_t)(m0 + row) * K + k0 + kk];
            }
        }
        // ---- stage B tile [32 k][128 n] -> Bs[n][k] (convert + transpose) ----
#pragma unroll
        for (int it = 0; it < 4; ++it) {
            int idx = (it * 256 + tid) * 4;           // 4096 f32
            int row = idx >> 7, col = idx & 127;      // row = k, col = n
            float4 v = *(const float4*)&Bf[(size_t)(k0 + row) * N + n0 + col];
            Bs[(col + 0) * 32 + row] = f2bf(v.x);
            Bs[(col + 1) * 32 + row] = f2bf(v.y);
            Bs[(col + 2) * 32 + row] = f2bf(v.z);
            Bs[(col + 3) * 32 + row] = f2bf(v.w);
        }
        __syncthreads();
        short8 af[4], bfr[4];
#pragma unroll
        for (int i = 0; i < 4; ++i)
            af[i] = *(const short8*)&As[(wr * 64 + i * 16 + ln) * 32 + qd * 8];
#pragma unroll
        for (int j = 0; j < 4; ++j)
            bfr[j] = *(const short8*)&Bs[(wc * 64 + j * 16 + ln) * 32 + qd * 8];
#pragma unroll
        for (int i = 0; i < 4; ++i)
#pragma unroll
            for (int j = 0; j < 4; ++j)
                acc[i][j] = __builtin_amdgcn_mfma_f32_16x16x32_bf16(af[i], bfr[j], acc[i][j], 0, 0, 0);
        __syncthreads();
    }
#pragma unroll
    for (int i = 0; i < 4; ++i)
#pragma unroll
        for (int j = 0; j < 4; ++j)
#pragma unroll
            for (int r = 0; r < 4; ++r) {
                int row = m0 + wr * 64 + i * 16 + qd * 4 + r;
                int col = n0 + wc * 64 + j * 16 + ln;
                if (OUT_F32)
                    ((float*)Cv)[(size_t)row * N + col] = acc[i][j][r];
                else
                    ((u16*)Cv)[(size_t)row * N + col] = f2bf(acc[i][j][r]);
            }
}

// ---------------- RoPE (in-place on bf16, optional scale fold) -------------
__global__ void rope_k(u16* __restrict__ buf, int nheads, float scale) {
    int total = B_ * S_ * nheads * (HD_ / 2);
    int i = blockIdx.x * blockDim.x + threadIdx.x;
    if (i >= total) return;
    int p = i & 63;                       // pair index 0..63
    int h = (i >> 6) % nheads;
    int row = i / (64 * nheads);          // b*S + s
    int s = row & (S_ - 1);
    float freq = __expf(-(float)(2 * p) * (9.210340371976184f / 128.0f)); // 10000^(-2p/128)
    float ang = (float)s * freq;
    float c, sn;
    sincosf(ang, &sn, &c);                // sincosf(x, sin*, cos*) — sin FIRST
    size_t base = ((size_t)row * nheads + h) * HD_ + 2 * p;
    float x0 = bf2f(buf[base]), x1 = bf2f(buf[base + 1]);
    buf[base]     = f2bf((x0 * c - x1 * sn) * scale);
    buf[base + 1] = f2bf((x0 * sn + x1 * c) * scale);
}

// ---------------- flash attention ------------------------------------------
// grid: (S/64, NH, B), block 256 (4 waves). Each wave owns 16 q-rows.
__global__ __launch_bounds__(256) void attn_k(const u16* __restrict__ Q,   // [B*S][NH*HD] rope'd+scaled
                                              const u16* __restrict__ K,   // [B*S][NKV*HD] rope'd
                                              const u16* __restrict__ Vt,  // [B][NKV][HD][S]
                                              u16* __restrict__ AO) {      // [B*S][NH*HD]
    __shared__ __align__(16) u16 Ks[64 * 128];    // [sk][d]
    __shared__ __align__(16) u16 Vts[128 * 64];   // [d][sk]
    __shared__ __align__(16) u16 Ps[4][16 * 64];  // per-wave probs [qrow][sk]

    int tid = threadIdx.x;
    int w = tid >> 6, lane = tid & 63;
    int ln = lane & 15, qd = lane >> 4;

    int qt = blockIdx.x;
    int h  = blockIdx.y;
    int b  = blockIdx.z;
    int g  = h >> 2;                // NREP = 4
    int q0 = qt * 64;

    int qrow = q0 + w * 16 + ln;
    const u16* qptr = Q + ((size_t)(b * S_ + qrow)) * (NH_ * HD_) + h * HD_;
    short8 aq[4];
#pragma unroll
    for (int kq = 0; kq < 4; ++kq)
        aq[kq] = *(const short8*)(qptr + kq * 32 + qd * 8);

    f32x4 oacc[8];
#pragma unroll
    for (int jd = 0; jd < 8; ++jd) oacc[jd] = f32x4{0.f, 0.f, 0.f, 0.f};
    float m_r[4] = {-1e30f, -1e30f, -1e30f, -1e30f};
    float l_r[4] = {0.f, 0.f, 0.f, 0.f};

    const u16* Kbase  = K + (size_t)(b * S_) * (NKV_ * HD_) + g * HD_;
    const u16* Vtbase = Vt + ((size_t)(b * NKV_ + g)) * HD_ * S_;

    int nk = qt + 1;
    for (int kt = 0; kt < nk; ++kt) {
        int k0 = kt * 64;
#pragma unroll
        for (int it = 0; it < 4; ++it) {
            int idx = (it * 256 + tid) * 8;
            int row = idx >> 7, col = idx & 127;
            *(int4*)&Ks[row * 128 + col] =
                *(const int4*)(Kbase + (size_t)(k0 + row) * (NKV_ * HD_) + col);
        }
#pragma unroll
        for (int it = 0; it < 4; ++it) {
            int idx = (it * 256 + tid) * 8;
            int row = idx >> 6, col = idx & 63;
            *(int4*)&Vts[row * 64 + col] =
                *(const int4*)(Vtbase + (size_t)row * S_ + k0 + col);
        }
        __syncthreads();

        f32x4 pacc[4];
#pragma unroll
        for (int j = 0; j < 4; ++j) pacc[j] = f32x4{0.f, 0.f, 0.f, 0.f};
#pragma unroll
        for (int j = 0; j < 4; ++j)
#pragma unroll
            for (int kq = 0; kq < 4; ++kq) {
                short8 bfr = *(const short8*)&Ks[(j * 16 + ln) * 128 + kq * 32 + qd * 8];
                pacc[j] = __builtin_amdgcn_mfma_f32_16x16x32_bf16(aq[kq], bfr, pacc[j], 0, 0, 0);
            }

        float mx[4] = {-1e30f, -1e30f, -1e30f, -1e30f};
#pragma unroll
        for (int j = 0; j < 4; ++j) {
            int kidx = k0 + j * 16 + ln;
#pragma unroll
            for (int r = 0; r < 4; ++r) {
                int qidx = q0 + w * 16 + qd * 4 + r;
                if (kidx > qidx) pacc[j][r] = -1e30f;
                mx[r] = fmaxf(mx[r], pacc[j][r]);
            }
        }
#pragma unroll
        for (int r = 0; r < 4; ++r) {
#pragma unroll
            for (int o = 1; o < 16; o <<= 1)
                mx[r] = fmaxf(mx[r], __shfl_xor(mx[r], o, 64));
        }
        float alpha[4], rs[4];
#pragma unroll
        for (int r = 0; r < 4; ++r) {
            float mn = fmaxf(m_r[r], mx[r]);
            alpha[r] = __expf(m_r[r] - mn);
            m_r[r] = mn;
            rs[r] = 0.f;
        }
#pragma unroll
        for (int j = 0; j < 4; ++j)
#pragma unroll
            for (int r = 0; r < 4; ++r) {
                float pv = __expf(pacc[j][r] - m_r[r]);
                rs[r] += pv;
                Ps[w][(qd * 4 + r) * 64 + j * 16 + ln] = f2bf(pv);
            }
#pragma unroll
        for (int r = 0; r < 4; ++r) {
#pragma unroll
            for (int o = 1; o < 16; o <<= 1)
                rs[r] += __shfl_xor(rs[r], o, 64);
            l_r[r] = l_r[r] * alpha[r] + rs[r];
        }
#pragma unroll
        for (int jd = 0; jd < 8; ++jd)
#pragma unroll
            for (int r = 0; r < 4; ++r) oacc[jd][r] *= alpha[r];

#pragma unroll
        for (int kq2 = 0; kq2 < 2; ++kq2) {
            short8 ap = *(const short8*)&Ps[w][ln * 64 + kq2 * 32 + qd * 8];
#pragma unroll
            for (int jd = 0; jd < 8; ++jd) {
                short8 bv = *(const short8*)&Vts[(jd * 16 + ln) * 64 + kq2 * 32 + qd * 8];
                oacc[jd] = __builtin_amdgcn_mfma_f32_16x16x32_bf16(ap, bv, oacc[jd], 0, 0, 0);
            }
        }
        __syncthreads();
    }

#pragma unroll
    for (int r = 0; r < 4; ++r) {
        float inv = 1.0f / l_r[r];
        int row = b * S_ + q0 + w * 16 + qd * 4 + r;
#pragma unroll
        for (int jd = 0; jd < 8; ++jd)
            AO[(size_t)row * (NH_ * HD_) + h * HD_ + jd * 16 + ln] = f2bf(oacc[jd][r] * inv);
    }
}

extern "C" void kernel_launch(void* const* d_in, const int* in_sizes, int n_in,
                              void* d_out, int out_size, void* d_ws, size_t ws_size,
                              hipStream_t stream) {
    const float* x  = (const float*)d_in[0];
    const float* wq = (const float*)d_in[1];
    const float* wk = (const float*)d_in[2];
    const float* wv = (const float*)d_in[3];
    const float* wo = (const float*)d_in[4];
    float* out = (float*)d_out;

    char* p = (char*)d_ws;
    auto alloc = [&](size_t nelem) { u16* r = (u16*)p; p += nelem * 2; return r; };
    u16* Q  = alloc(4096ull * 4096);   // 33.5 MB
    u16* Kb = alloc(4096ull * 1024);   //  8.4 MB
    u16* Vb = alloc(4096ull * 1024);   //  8.4 MB
    u16* Vt = alloc(4096ull * 1024);   //  8.4 MB
    u16* AO = alloc(4096ull * 4096);   // 33.5 MB  -> total ~92 MB

    // projections (f32 A, f32 B converted+transposed in staging, bf16 out)
    gemm_nt<1, 0><<<dim3(32, 32), 256, 0, stream>>>(x, wq, Q, 4096, 4096, 4096);
    gemm_nt<1, 0><<<dim3(8, 32), 256, 0, stream>>>(x, wk, Kb, 4096, 1024, 4096);
    gemm_nt<1, 0><<<dim3(8, 32), 256, 0, stream>>>(x, wv, Vb, 4096, 1024, 4096);

    // RoPE (scale 1/sqrt(128) folded into Q)
    int totq = B_ * S_ * NH_ * (HD_ / 2);
    rope_k<<<(totq + 255) / 256, 256, 0, stream>>>(Q, NH_, 0.08838834764831845f);
    int totk = B_ * S_ * NKV_ * (HD_ / 2);
    rope_k<<<(totk + 255) / 256, 256, 0, stream>>>(Kb, NKV_, 1.0f);

    // V -> Vt [B][NKV][HD][S]
    dim3 tblk(64, 4);
    for (int b = 0; b < B_; ++b)
        transpose_k<<<dim3(16, 32), tblk, 0, stream>>>(
            Vb + (size_t)b * S_ * (NKV_ * HD_), Vt + (size_t)b * (NKV_ * HD_) * S_, S_, NKV_ * HD_);

    // attention
    attn_k<<<dim3(S_ / 64, NH_, B_), 256, 0, stream>>>(Q, Kb, Vt, AO);

    // out projection -> f32 d_out
    gemm_nt<0, 1><<<dim3(32, 32), 256, 0, stream>>>(AO, wo, out, 4096, 4096, 4096);
}

// Round 4
// 1393.515 us; speedup vs baseline: 2.5934x; 2.5934x over previous
//
#include <hip/hip_runtime.h>
#include <hip/hip_bf16.h>

#define B_ 2
#define S_ 2048
#define D_ 4096
#define NH_ 32
#define NKV_ 8
#define HD_ 128
#define NREP_ 4

typedef unsigned short u16;
typedef __attribute__((ext_vector_type(8))) short short8;
typedef __attribute__((ext_vector_type(4))) float f32x4;

__device__ inline float bf2f(u16 u) {
    union { unsigned u; float f; } v; v.u = ((unsigned)u) << 16; return v.f;
}
__device__ inline u16 f2bf(float f) {
    union { float f; unsigned u; } v; v.f = f;
    unsigned r = v.u + 0x7fffu + ((v.u >> 16) & 1u);
    return (u16)(r >> 16);
}

// async global->LDS, 16 bytes/lane. LDS base must be wave-uniform; HW scatters
// lane i to ldsbase + i*16 (m97-verified). No LDS padding allowed.
__device__ inline void gl_lds16(const u16* g, u16* l) {
    __builtin_amdgcn_global_load_lds(
        (const __attribute__((address_space(1))) unsigned int*)g,
        (__attribute__((address_space(3))) unsigned int*)l, 16, 0, 0);
}

// ---------------- elementwise f32 -> bf16 ----------------------------------
__global__ __launch_bounds__(256) void conv_k(const float* __restrict__ in,
                                              u16* __restrict__ out) {
    size_t i = ((size_t)blockIdx.x * 256 + threadIdx.x) * 4;
    float4 v = *(const float4*)&in[i];
    u16 t[4] = {f2bf(v.x), f2bf(v.y), f2bf(v.z), f2bf(v.w)};
    *(uint2*)&out[i] = *(const uint2*)t;
}

// ---------------- transpose+convert: f32 in [R][C] -> bf16 out [C][R] ------
__global__ __launch_bounds__(256) void tconv_k(const float* __restrict__ in,
                                               u16* __restrict__ out,
                                               int R, int C) {
    __shared__ u16 tile[64][65];
    int bx = blockIdx.x * 64, by = blockIdx.y * 64;
    int tx = threadIdx.x, ty = threadIdx.y;       // 64, 4
    for (int i = ty; i < 64; i += 4)
        tile[i][tx] = f2bf(in[(size_t)(by + i) * C + bx + tx]);
    __syncthreads();
    for (int i = ty; i < 64; i += 4)
        out[(size_t)(bx + i) * R + by + tx] = tile[tx][i];
}

// ---------------- transpose bf16: in [R][C] -> out [C][R] ------------------
__global__ __launch_bounds__(256) void transpose_k(const u16* __restrict__ in,
                                                   u16* __restrict__ out,
                                                   int R, int C) {
    __shared__ u16 tile[64][65];
    int bx = blockIdx.x * 64, by = blockIdx.y * 64;
    int tx = threadIdx.x, ty = threadIdx.y;
    for (int i = ty; i < 64; i += 4)
        tile[i][tx] = in[(size_t)(by + i) * C + bx + tx];
    __syncthreads();
    for (int i = ty; i < 64; i += 4)
        out[(size_t)(bx + i) * R + by + tx] = tile[tx][i];
}

// ---------------- GEMM (m97 structure): C[M][N] = A[M][K] * Bt[N][K]^T -----
// bf16 A/Bt, f32 accum; out bf16 or f32. 128x128 tile, BK=32,
// global_load_lds width-16 staging, 2-barrier K-loop.
template <int OUT_F32>
__global__ __launch_bounds__(256) void gemm_bt(const u16* __restrict__ A,
                                               const u16* __restrict__ Bt,
                                               void* __restrict__ Cv,
                                               int M, int N, int K) {
    __shared__ __align__(16) u16 As[128 * 32];   // [m][k] unpadded (DMA layout)
    __shared__ __align__(16) u16 Bs[128 * 32];   // [n][k]
    int tid = threadIdx.x;
    int w = tid >> 6, lane = tid & 63;
    int ln = lane & 15, qd = lane >> 4;
    int wr = w >> 1, wc = w & 1;
    int m0 = blockIdx.y * 128, n0 = blockIdx.x * 128;

    // lane's slice of the wave's 16-row staging segment
    int srow = lane >> 2;          // 0..15
    int skk  = (lane & 3) * 8;     // 0,8,16,24
    const u16* Ag = A  + (size_t)(m0 + w * 32 + srow) * K + skk;
    const u16* Bg = Bt + (size_t)(n0 + w * 32 + srow) * K + skk;

    f32x4 acc[4][4];
#pragma unroll
    for (int i = 0; i < 4; ++i)
#pragma unroll
        for (int j = 0; j < 4; ++j)
            acc[i][j] = f32x4{0.f, 0.f, 0.f, 0.f};

    for (int k0 = 0; k0 < K; k0 += 32) {
#pragma unroll
        for (int t = 0; t < 2; ++t) {
            gl_lds16(Ag + (size_t)(t * 16) * K + k0, &As[(w * 32 + t * 16) * 32]);
            gl_lds16(Bg + (size_t)(t * 16) * K + k0, &Bs[(w * 32 + t * 16) * 32]);
        }
        __syncthreads();
        short8 af[4], bfr[4];
#pragma unroll
        for (int i = 0; i < 4; ++i)
            af[i] = *(const short8*)&As[(wr * 64 + i * 16 + ln) * 32 + qd * 8];
#pragma unroll
        for (int j = 0; j < 4; ++j)
            bfr[j] = *(const short8*)&Bs[(wc * 64 + j * 16 + ln) * 32 + qd * 8];
#pragma unroll
        for (int i = 0; i < 4; ++i)
#pragma unroll
            for (int j = 0; j < 4; ++j)
                acc[i][j] = __builtin_amdgcn_mfma_f32_16x16x32_bf16(af[i], bfr[j], acc[i][j], 0, 0, 0);
        __syncthreads();
    }
#pragma unroll
    for (int i = 0; i < 4; ++i)
#pragma unroll
        for (int j = 0; j < 4; ++j)
#pragma unroll
            for (int r = 0; r < 4; ++r) {
                int row = m0 + wr * 64 + i * 16 + qd * 4 + r;
                int col = n0 + wc * 64 + j * 16 + ln;
                if (OUT_F32)
                    ((float*)Cv)[(size_t)row * N + col] = acc[i][j][r];
                else
                    ((u16*)Cv)[(size_t)row * N + col] = f2bf(acc[i][j][r]);
            }
}

// ---------------- RoPE (in-place on bf16, optional scale fold) -------------
__global__ void rope_k(u16* __restrict__ buf, int nheads, float scale) {
    int total = B_ * S_ * nheads * (HD_ / 2);
    int i = blockIdx.x * blockDim.x + threadIdx.x;
    if (i >= total) return;
    int p = i & 63;
    int h = (i >> 6) % nheads;
    int row = i / (64 * nheads);
    int s = row & (S_ - 1);
    float freq = __expf(-(float)(2 * p) * (9.210340371976184f / 128.0f));
    float ang = (float)s * freq;
    float c, sn;
    sincosf(ang, &sn, &c);                // sincosf(x, sin*, cos*)
    size_t base = ((size_t)row * nheads + h) * HD_ + 2 * p;
    float x0 = bf2f(buf[base]), x1 = bf2f(buf[base + 1]);
    buf[base]     = f2bf((x0 * c - x1 * sn) * scale);
    buf[base + 1] = f2bf((x0 * sn + x1 * c) * scale);
}

// ---------------- flash attention ------------------------------------------
__global__ __launch_bounds__(256) void attn_k(const u16* __restrict__ Q,
                                              const u16* __restrict__ K,
                                              const u16* __restrict__ Vt,
                                              u16* __restrict__ AO) {
    __shared__ __align__(16) u16 Ks[64 * 128];
    __shared__ __align__(16) u16 Vts[128 * 64];
    __shared__ __align__(16) u16 Ps[4][16 * 64];

    int tid = threadIdx.x;
    int w = tid >> 6, lane = tid & 63;
    int ln = lane & 15, qd = lane >> 4;

    int qt = blockIdx.x;
    int h  = blockIdx.y;
    int b  = blockIdx.z;
    int g  = h >> 2;
    int q0 = qt * 64;

    int qrow = q0 + w * 16 + ln;
    const u16* qptr = Q + ((size_t)(b * S_ + qrow)) * (NH_ * HD_) + h * HD_;
    short8 aq[4];
#pragma unroll
    for (int kq = 0; kq < 4; ++kq)
        aq[kq] = *(const short8*)(qptr + kq * 32 + qd * 8);

    f32x4 oacc[8];
#pragma unroll
    for (int jd = 0; jd < 8; ++jd) oacc[jd] = f32x4{0.f, 0.f, 0.f, 0.f};
    float m_r[4] = {-1e30f, -1e30f, -1e30f, -1e30f};
    float l_r[4] = {0.f, 0.f, 0.f, 0.f};

    const u16* Kbase  = K + (size_t)(b * S_) * (NKV_ * HD_) + g * HD_;
    const u16* Vtbase = Vt + ((size_t)(b * NKV_ + g)) * HD_ * S_;

    int nk = qt + 1;
    for (int kt = 0; kt < nk; ++kt) {
        int k0 = kt * 64;
#pragma unroll
        for (int it = 0; it < 4; ++it) {
            int idx = (it * 256 + tid) * 8;
            int row = idx >> 7, col = idx & 127;
            *(int4*)&Ks[row * 128 + col] =
                *(const int4*)(Kbase + (size_t)(k0 + row) * (NKV_ * HD_) + col);
        }
#pragma unroll
        for (int it = 0; it < 4; ++it) {
            int idx = (it * 256 + tid) * 8;
            int row = idx >> 6, col = idx & 63;
            *(int4*)&Vts[row * 64 + col] =
                *(const int4*)(Vtbase + (size_t)row * S_ + k0 + col);
        }
        __syncthreads();

        f32x4 pacc[4];
#pragma unroll
        for (int j = 0; j < 4; ++j) pacc[j] = f32x4{0.f, 0.f, 0.f, 0.f};
#pragma unroll
        for (int j = 0; j < 4; ++j)
#pragma unroll
            for (int kq = 0; kq < 4; ++kq) {
                short8 bfr = *(const short8*)&Ks[(j * 16 + ln) * 128 + kq * 32 + qd * 8];
                pacc[j] = __builtin_amdgcn_mfma_f32_16x16x32_bf16(aq[kq], bfr, pacc[j], 0, 0, 0);
            }

        float mx[4] = {-1e30f, -1e30f, -1e30f, -1e30f};
#pragma unroll
        for (int j = 0; j < 4; ++j) {
            int kidx = k0 + j * 16 + ln;
#pragma unroll
            for (int r = 0; r < 4; ++r) {
                int qidx = q0 + w * 16 + qd * 4 + r;
                if (kidx > qidx) pacc[j][r] = -1e30f;
                mx[r] = fmaxf(mx[r], pacc[j][r]);
            }
        }
#pragma unroll
        for (int r = 0; r < 4; ++r) {
#pragma unroll
            for (int o = 1; o < 16; o <<= 1)
                mx[r] = fmaxf(mx[r], __shfl_xor(mx[r], o, 64));
        }
        float alpha[4], rs[4];
#pragma unroll
        for (int r = 0; r < 4; ++r) {
            float mn = fmaxf(m_r[r], mx[r]);
            alpha[r] = __expf(m_r[r] - mn);
            m_r[r] = mn;
            rs[r] = 0.f;
        }
#pragma unroll
        for (int j = 0; j < 4; ++j)
#pragma unroll
            for (int r = 0; r < 4; ++r) {
                float pv = __expf(pacc[j][r] - m_r[r]);
                rs[r] += pv;
                Ps[w][(qd * 4 + r) * 64 + j * 16 + ln] = f2bf(pv);
            }
#pragma unroll
        for (int r = 0; r < 4; ++r) {
#pragma unroll
            for (int o = 1; o < 16; o <<= 1)
                rs[r] += __shfl_xor(rs[r], o, 64);
            l_r[r] = l_r[r] * alpha[r] + rs[r];
        }
#pragma unroll
        for (int jd = 0; jd < 8; ++jd)
#pragma unroll
            for (int r = 0; r < 4; ++r) oacc[jd][r] *= alpha[r];

#pragma unroll
        for (int kq2 = 0; kq2 < 2; ++kq2) {
            short8 ap = *(const short8*)&Ps[w][ln * 64 + kq2 * 32 + qd * 8];
#pragma unroll
            for (int jd = 0; jd < 8; ++jd) {
                short8 bv = *(const short8*)&Vts[(jd * 16 + ln) * 64 + kq2 * 32 + qd * 8];
                oacc[jd] = __builtin_amdgcn_mfma_f32_16x16x32_bf16(ap, bv, oacc[jd], 0, 0, 0);
            }
        }
        __syncthreads();
    }

#pragma unroll
    for (int r = 0; r < 4; ++r) {
        float inv = 1.0f / l_r[r];
        int row = b * S_ + q0 + w * 16 + qd * 4 + r;
#pragma unroll
        for (int jd = 0; jd < 8; ++jd)
            AO[(size_t)row * (NH_ * HD_) + h * HD_ + jd * 16 + ln] = f2bf(oacc[jd][r] * inv);
    }
}

extern "C" void kernel_launch(void* const* d_in, const int* in_sizes, int n_in,
                              void* d_out, int out_size, void* d_ws, size_t ws_size,
                              hipStream_t stream) {
    const float* x  = (const float*)d_in[0];
    const float* wq = (const float*)d_in[1];
    const float* wk = (const float*)d_in[2];
    const float* wv = (const float*)d_in[3];
    const float* wo = (const float*)d_in[4];
    float* out = (float*)d_out;

    char* p = (char*)d_ws;
    auto alloc = [&](size_t nelem) { u16* r = (u16*)p; p += nelem * 2; return r; };
    u16* xb  = alloc(4096ull * 4096);   // 32 MB  (aliased by woT after projections)
    u16* wqT = alloc(4096ull * 4096);   // 32 MB  (aliased by Vt after projections)
    u16* wkT = alloc(1024ull * 4096);   //  8 MB
    u16* wvT = alloc(1024ull * 4096);   //  8 MB
    u16* Q   = alloc(4096ull * 4096);   // 32 MB
    u16* Kb  = alloc(4096ull * 1024);   //  8 MB
    u16* Vb  = alloc(4096ull * 1024);   //  8 MB
    u16* AO  = alloc(4096ull * 4096);   // 32 MB   -> 160 MB peak

    dim3 tblk(64, 4);
    // one-shot converts: x -> bf16, weights -> bf16 transposed [N][K]
    conv_k<<<16384, 256, 0, stream>>>(x, xb);
    tconv_k<<<dim3(64, 64), tblk, 0, stream>>>(wq, wqT, 4096, 4096);
    tconv_k<<<dim3(16, 64), tblk, 0, stream>>>(wk, wkT, 4096, 1024);
    tconv_k<<<dim3(16, 64), tblk, 0, stream>>>(wv, wvT, 4096, 1024);

    // projections (pure bf16, m97-style global_load_lds staging)
    gemm_bt<0><<<dim3(32, 32), 256, 0, stream>>>(xb, wqT, Q, 4096, 4096, 4096);
    gemm_bt<0><<<dim3(8, 32), 256, 0, stream>>>(xb, wkT, Kb, 4096, 1024, 4096);
    gemm_bt<0><<<dim3(8, 32), 256, 0, stream>>>(xb, wvT, Vb, 4096, 1024, 4096);

    // wo^T into xb's slot (x dead), V^T into wqT's slot (wqT dead)
    u16* woT = xb;
    u16* Vt  = wqT;
    tconv_k<<<dim3(64, 64), tblk, 0, stream>>>(wo, woT, 4096, 4096);

    // RoPE (1/sqrt(128) folded into Q)
    int totq = B_ * S_ * NH_ * (HD_ / 2);
    rope_k<<<(totq + 255) / 256, 256, 0, stream>>>(Q, NH_, 0.08838834764831845f);
    int totk = B_ * S_ * NKV_ * (HD_ / 2);
    rope_k<<<(totk + 255) / 256, 256, 0, stream>>>(Kb, NKV_, 1.0f);

    // V -> Vt [B][NKV][HD][S]
    for (int b = 0; b < B_; ++b)
        transpose_k<<<dim3(16, 32), tblk, 0, stream>>>(
            Vb + (size_t)b * S_ * (NKV_ * HD_), Vt + (size_t)b * (NKV_ * HD_) * S_, S_, NKV_ * HD_);

    // attention
    attn_k<<<dim3(S_ / 64, NH_, B_), 256, 0, stream>>>(Q, Kb, Vt, AO);

    // out projection -> f32 d_out
    gemm_bt<1><<<dim3(32, 32), 256, 0, stream>>>(AO, woT, out, 4096, 4096, 4096);
}

// Round 5
// 1081.040 us; speedup vs baseline: 3.3430x; 1.2891x over previous
//
#include <hip/hip_runtime.h>
#include <hip/hip_bf16.h>

#define B_ 2
#define S_ 2048
#define D_ 4096
#define NH_ 32
#define NKV_ 8
#define HD_ 128
#define NREP_ 4

typedef unsigned short u16;
typedef __attribute__((ext_vector_type(8))) short short8;
typedef __attribute__((ext_vector_type(4))) float f32x4;

__device__ inline float bf2f(u16 u) {
    union { unsigned u; float f; } v; v.u = ((unsigned)u) << 16; return v.f;
}
__device__ inline u16 f2bf(float f) {
    union { float f; unsigned u; } v; v.f = f;
    unsigned r = v.u + 0x7fffu + ((v.u >> 16) & 1u);
    return (u16)(r >> 16);
}
__device__ inline unsigned pack_bf16(float a, float b) {
    return (unsigned)f2bf(a) | ((unsigned)f2bf(b) << 16);
}

// async global->LDS, 16 bytes/lane (m97-verified). LDS base wave-uniform.
__device__ inline void gl_lds16(const u16* g, u16* l) {
    __builtin_amdgcn_global_load_lds(
        (const __attribute__((address_space(1))) unsigned int*)g,
        (__attribute__((address_space(3))) unsigned int*)l, 16, 0, 0);
}

// ---------------- elementwise f32 -> bf16 ----------------------------------
__global__ __launch_bounds__(256) void conv_k(const float* __restrict__ in,
                                              u16* __restrict__ out) {
    size_t i = ((size_t)blockIdx.x * 256 + threadIdx.x) * 4;
    float4 v = *(const float4*)&in[i];
    u16 t[4] = {f2bf(v.x), f2bf(v.y), f2bf(v.z), f2bf(v.w)};
    *(uint2*)&out[i] = *(const uint2*)t;
}

// ---------------- transpose+convert: f32 in [R][C] -> bf16 out [C][R] ------
__global__ __launch_bounds__(256) void tconv_k(const float* __restrict__ in,
                                               u16* __restrict__ out,
                                               int R, int C) {
    __shared__ u16 tile[64][65];
    int bx = blockIdx.x * 64, by = blockIdx.y * 64;
    int tx = threadIdx.x, ty = threadIdx.y;
    for (int i = ty; i < 64; i += 4)
        tile[i][tx] = f2bf(in[(size_t)(by + i) * C + bx + tx]);
    __syncthreads();
    for (int i = ty; i < 64; i += 4)
        out[(size_t)(bx + i) * R + by + tx] = tile[tx][i];
}

// ---------------- transpose bf16: in [R][C] -> out [C][R] ------------------
__global__ __launch_bounds__(256) void transpose_k(const u16* __restrict__ in,
                                                   u16* __restrict__ out,
                                                   int R, int C) {
    __shared__ u16 tile[64][65];
    int bx = blockIdx.x * 64, by = blockIdx.y * 64;
    int tx = threadIdx.x, ty = threadIdx.y;
    for (int i = ty; i < 64; i += 4)
        tile[i][tx] = in[(size_t)(by + i) * C + bx + tx];
    __syncthreads();
    for (int i = ty; i < 64; i += 4)
        out[(size_t)(bx + i) * R + by + tx] = tile[tx][i];
}

// ---------------- GEMM (m97 structure): C[M][N] = A[M][K] * Bt[N][K]^T -----
template <int OUT_F32>
__global__ __launch_bounds__(256) void gemm_bt(const u16* __restrict__ A,
                                               const u16* __restrict__ Bt,
                                               void* __restrict__ Cv,
                                               int M, int N, int K) {
    __shared__ __align__(16) u16 As[128 * 32];   // [m][k] unpadded (DMA layout)
    __shared__ __align__(16) u16 Bs[128 * 32];   // [n][k]
    int tid = threadIdx.x;
    int w = tid >> 6, lane = tid & 63;
    int ln = lane & 15, qd = lane >> 4;
    int wr = w >> 1, wc = w & 1;
    int m0 = blockIdx.y * 128, n0 = blockIdx.x * 128;

    int srow = lane >> 2;
    int skk  = (lane & 3) * 8;
    const u16* Ag = A  + (size_t)(m0 + w * 32 + srow) * K + skk;
    const u16* Bg = Bt + (size_t)(n0 + w * 32 + srow) * K + skk;

    f32x4 acc[4][4];
#pragma unroll
    for (int i = 0; i < 4; ++i)
#pragma unroll
        for (int j = 0; j < 4; ++j)
            acc[i][j] = f32x4{0.f, 0.f, 0.f, 0.f};

    for (int k0 = 0; k0 < K; k0 += 32) {
#pragma unroll
        for (int t = 0; t < 2; ++t) {
            gl_lds16(Ag + (size_t)(t * 16) * K + k0, &As[(w * 32 + t * 16) * 32]);
            gl_lds16(Bg + (size_t)(t * 16) * K + k0, &Bs[(w * 32 + t * 16) * 32]);
        }
        __syncthreads();
        short8 af[4], bfr[4];
#pragma unroll
        for (int i = 0; i < 4; ++i)
            af[i] = *(const short8*)&As[(wr * 64 + i * 16 + ln) * 32 + qd * 8];
#pragma unroll
        for (int j = 0; j < 4; ++j)
            bfr[j] = *(const short8*)&Bs[(wc * 64 + j * 16 + ln) * 32 + qd * 8];
#pragma unroll
        for (int i = 0; i < 4; ++i)
#pragma unroll
            for (int j = 0; j < 4; ++j)
                acc[i][j] = __builtin_amdgcn_mfma_f32_16x16x32_bf16(af[i], bfr[j], acc[i][j], 0, 0, 0);
        __syncthreads();
    }
#pragma unroll
    for (int i = 0; i < 4; ++i)
#pragma unroll
        for (int j = 0; j < 4; ++j)
#pragma unroll
            for (int r = 0; r < 4; ++r) {
                int row = m0 + wr * 64 + i * 16 + qd * 4 + r;
                int col = n0 + wc * 64 + j * 16 + ln;
                if (OUT_F32)
                    ((float*)Cv)[(size_t)row * N + col] = acc[i][j][r];
                else
                    ((u16*)Cv)[(size_t)row * N + col] = f2bf(acc[i][j][r]);
            }
}

// ---------------- RoPE (in-place on bf16, optional scale fold) -------------
__global__ void rope_k(u16* __restrict__ buf, int nheads, float scale) {
    int total = B_ * S_ * nheads * (HD_ / 2);
    int i = blockIdx.x * blockDim.x + threadIdx.x;
    if (i >= total) return;
    int p = i & 63;
    int h = (i >> 6) % nheads;
    int row = i / (64 * nheads);
    int s = row & (S_ - 1);
    float freq = __expf(-(float)(2 * p) * (9.210340371976184f / 128.0f));
    float ang = (float)s * freq;
    float c, sn;
    sincosf(ang, &sn, &c);                // sincosf(x, sin*, cos*)
    size_t base = ((size_t)row * nheads + h) * HD_ + 2 * p;
    float x0 = bf2f(buf[base]), x1 = bf2f(buf[base + 1]);
    buf[base]     = f2bf((x0 * c - x1 * sn) * scale);
    buf[base + 1] = f2bf((x0 * sn + x1 * c) * scale);
}

// ---------------- flash attention (transposed-S form) ----------------------
// grid (S/128, NH, B), 512 threads (8 waves); wave w owns q-rows q0+w*16..+15.
// S^T = K·Q^T (C/D: row=key, col=q=ln); softmax per-lane over 16 regs + 2
// shfl_xor; P~^T B-frag built via 8 shfls/kstep; O^T = V^T·P~^T.
__global__ __launch_bounds__(512) void attn_k(const u16* __restrict__ Q,
                                              const u16* __restrict__ K,
                                              const u16* __restrict__ Vt,
                                              u16* __restrict__ AO) {
    __shared__ __align__(16) u16 Ks[2][64 * 136];    // [sk][d] pad->136
    __shared__ __align__(16) u16 Vts[2][128 * 72];   // [d][sk] pad->72

    int tid = threadIdx.x;
    int w = tid >> 6, lane = tid & 63;
    int ln = lane & 15, qd = lane >> 4;

    int qt = blockIdx.x;
    int h  = blockIdx.y;
    int b  = blockIdx.z;
    int g  = h >> 2;
    int q0 = qt * 128;

    // Q B-frag: B[k=hd][n=q=ln]
    const u16* qptr = Q + ((size_t)(b * S_ + q0 + w * 16 + ln)) * (NH_ * HD_) + h * HD_;
    short8 bq[4];
#pragma unroll
    for (int kq = 0; kq < 4; ++kq)
        bq[kq] = *(const short8*)(qptr + kq * 32 + qd * 8);

    f32x4 ot[8];                      // O^T: d = db*16+qd*4+r, q = ln
#pragma unroll
    for (int db = 0; db < 8; ++db) ot[db] = f32x4{0.f, 0.f, 0.f, 0.f};
    float m_s = -1e30f, l_s = 0.f;

    const u16* Kbase = K + (size_t)(b * S_) * (NKV_ * HD_) + g * HD_;
    const u16* Vtb   = Vt + ((size_t)(b * NKV_ + g)) * HD_ * S_;

    int nk = 2 * qt + 2;
    int qg = q0 + w * 16 + ln;        // this lane's q row
    int qmaxw = q0 + w * 16 + 15;     // wave's max q

    // staging map (per thread, per tile): Ks chunks c=tid,tid+512 (row=c>>4,
    // blk=c&15); Vts chunks c=tid,tid+512 (row=c>>3, blk=c&7)
    int kr0 = tid >> 4, kb0 = (tid & 15) * 8;
    int kr1 = (tid + 512) >> 4, kb1 = kb0;           // (tid+512)&15 == tid&15
    int vr0 = tid >> 3, vb0 = (tid & 7) * 8;
    int vr1 = (tid + 512) >> 3, vb1 = vb0;

    // prologue: stage tile 0 into buf 0
    {
        int4 a0 = *(const int4*)(Kbase + (size_t)kr0 * (NKV_ * HD_) + kb0);
        int4 a1 = *(const int4*)(Kbase + (size_t)kr1 * (NKV_ * HD_) + kb1);
        int4 v0 = *(const int4*)(Vtb + (size_t)vr0 * S_ + vb0);
        int4 v1 = *(const int4*)(Vtb + (size_t)vr1 * S_ + vb1);
        *(int4*)&Ks[0][kr0 * 136 + kb0] = a0;
        *(int4*)&Ks[0][kr1 * 136 + kb1] = a1;
        *(int4*)&Vts[0][vr0 * 72 + vb0] = v0;
        *(int4*)&Vts[0][vr1 * 72 + vb1] = v1;
    }
    __syncthreads();

    for (int kt = 0; kt < nk; ++kt) {
        int bb = kt & 1;
        int k0 = kt * 64;
        bool pf = (kt + 1 < nk);
        int4 pa0, pa1, pv0, pv1;
        if (pf) {
            int k0n = k0 + 64;
            pa0 = *(const int4*)(Kbase + (size_t)(k0n + kr0) * (NKV_ * HD_) + kb0);
            pa1 = *(const int4*)(Kbase + (size_t)(k0n + kr1) * (NKV_ * HD_) + kb1);
            pv0 = *(const int4*)(Vtb + (size_t)vr0 * S_ + k0n + vb0);
            pv1 = *(const int4*)(Vtb + (size_t)vr1 * S_ + k0n + vb1);
        }

        if (k0 <= qmaxw) {            // wave has at least one unmasked key
            // S^T = K Q^T : A = K-frag (m=key), B = Q-frag (n=q)
            f32x4 st[4];
#pragma unroll
            for (int kb = 0; kb < 4; ++kb) st[kb] = f32x4{0.f, 0.f, 0.f, 0.f};
#pragma unroll
            for (int kb = 0; kb < 4; ++kb)
#pragma unroll
                for (int kq = 0; kq < 4; ++kq) {
                    short8 ak = *(const short8*)&Ks[bb][(kb * 16 + ln) * 136 + kq * 32 + qd * 8];
                    st[kb] = __builtin_amdgcn_mfma_f32_16x16x32_bf16(ak, bq[kq], st[kb], 0, 0, 0);
                }
            // causal mask + running max (key = k0 + kb*16 + qd*4 + r, q = qg)
            float mx = -1e30f;
#pragma unroll
            for (int kb = 0; kb < 4; ++kb)
#pragma unroll
                for (int r = 0; r < 4; ++r) {
                    int kg = k0 + kb * 16 + qd * 4 + r;
                    if (kg > qg) st[kb][r] = -1e30f;
                    mx = fmaxf(mx, st[kb][r]);
                }
            mx = fmaxf(mx, __shfl_xor(mx, 16, 64));
            mx = fmaxf(mx, __shfl_xor(mx, 32, 64));
            float mn = fmaxf(m_s, mx);
            float alpha = __expf(m_s - mn);
            m_s = mn;
            float rs = 0.f;
#pragma unroll
            for (int kb = 0; kb < 4; ++kb)
#pragma unroll
                for (int r = 0; r < 4; ++r) {
                    float pv = __expf(st[kb][r] - mn);
                    st[kb][r] = pv;
                    rs += pv;
                }
            rs += __shfl_xor(rs, 16, 64);
            rs += __shfl_xor(rs, 32, 64);
            l_s = l_s * alpha + rs;
#pragma unroll
            for (int db = 0; db < 8; ++db)
#pragma unroll
                for (int r = 0; r < 4; ++r) ot[db][r] *= alpha;

            // pack P~ to bf16 pairs per keyblock
            unsigned pk[4][2];
#pragma unroll
            for (int kb = 0; kb < 4; ++kb) {
                pk[kb][0] = pack_bf16(st[kb][0], st[kb][1]);
                pk[kb][1] = pack_bf16(st[kb][2], st[kb][3]);
            }
            // O^T += V^T P~^T
            int sA = ((qd & 1) << 5) + ln;   // (2*(qd&1))*16 + ln
            int sB = sA + 16;
            bool hi = (qd & 2) != 0;
#pragma unroll
            for (int ks = 0; ks < 2; ++ks) {
                unsigned t0a = (unsigned)__shfl((int)pk[2 * ks][0], sA, 64);
                unsigned t0b = (unsigned)__shfl((int)pk[2 * ks][1], sA, 64);
                unsigned t1a = (unsigned)__shfl((int)pk[2 * ks + 1][0], sA, 64);
                unsigned t1b = (unsigned)__shfl((int)pk[2 * ks + 1][1], sA, 64);
                unsigned t2a = (unsigned)__shfl((int)pk[2 * ks][0], sB, 64);
                unsigned t2b = (unsigned)__shfl((int)pk[2 * ks][1], sB, 64);
                unsigned t3a = (unsigned)__shfl((int)pk[2 * ks + 1][0], sB, 64);
                unsigned t3b = (unsigned)__shfl((int)pk[2 * ks + 1][1], sB, 64);
                union { unsigned u[4]; short8 s8; } bp;
                bp.u[0] = hi ? t1a : t0a;
                bp.u[1] = hi ? t1b : t0b;
                bp.u[2] = hi ? t3a : t2a;
                bp.u[3] = hi ? t3b : t2b;
#pragma unroll
                for (int db = 0; db < 8; ++db) {
                    short8 av = *(const short8*)&Vts[bb][(db * 16 + ln) * 72 + ks * 32 + qd * 8];
                    ot[db] = __builtin_amdgcn_mfma_f32_16x16x32_bf16(av, bp.s8, ot[db], 0, 0, 0);
                }
            }
        }

        if (pf) {
            int nb = bb ^ 1;
            *(int4*)&Ks[nb][kr0 * 136 + kb0] = pa0;
            *(int4*)&Ks[nb][kr1 * 136 + kb1] = pa1;
            *(int4*)&Vts[nb][vr0 * 72 + vb0] = pv0;
            *(int4*)&Vts[nb][vr1 * 72 + vb1] = pv1;
        }
        __syncthreads();
    }

    // epilogue: O[q][d] = O^T / l
    float invl = 1.0f / l_s;
    size_t orow = (size_t)(b * S_ + q0 + w * 16 + ln) * (NH_ * HD_) + h * HD_;
#pragma unroll
    for (int db = 0; db < 8; ++db) {
        u16 t[4];
#pragma unroll
        for (int r = 0; r < 4; ++r) t[r] = f2bf(ot[db][r] * invl);
        *(uint2*)&AO[orow + db * 16 + qd * 4] = *(const uint2*)t;
    }
}

extern "C" void kernel_launch(void* const* d_in, const int* in_sizes, int n_in,
                              void* d_out, int out_size, void* d_ws, size_t ws_size,
                              hipStream_t stream) {
    const float* x  = (const float*)d_in[0];
    const float* wq = (const float*)d_in[1];
    const float* wk = (const float*)d_in[2];
    const float* wv = (const float*)d_in[3];
    const float* wo = (const float*)d_in[4];
    float* out = (float*)d_out;

    char* p = (char*)d_ws;
    auto alloc = [&](size_t nelem) { u16* r = (u16*)p; p += nelem * 2; return r; };
    u16* xb  = alloc(4096ull * 4096);   // aliased by woT after projections
    u16* wqT = alloc(4096ull * 4096);   // aliased by Vt after projections
    u16* wkT = alloc(1024ull * 4096);
    u16* wvT = alloc(1024ull * 4096);
    u16* Q   = alloc(4096ull * 4096);
    u16* Kb  = alloc(4096ull * 1024);
    u16* Vb  = alloc(4096ull * 1024);
    u16* AO  = alloc(4096ull * 4096);

    dim3 tblk(64, 4);
    conv_k<<<16384, 256, 0, stream>>>(x, xb);
    tconv_k<<<dim3(64, 64), tblk, 0, stream>>>(wq, wqT, 4096, 4096);
    tconv_k<<<dim3(16, 64), tblk, 0, stream>>>(wk, wkT, 4096, 1024);
    tconv_k<<<dim3(16, 64), tblk, 0, stream>>>(wv, wvT, 4096, 1024);

    gemm_bt<0><<<dim3(32, 32), 256, 0, stream>>>(xb, wqT, Q, 4096, 4096, 4096);
    gemm_bt<0><<<dim3(8, 32), 256, 0, stream>>>(xb, wkT, Kb, 4096, 1024, 4096);
    gemm_bt<0><<<dim3(8, 32), 256, 0, stream>>>(xb, wvT, Vb, 4096, 1024, 4096);

    u16* woT = xb;
    u16* Vt  = wqT;
    tconv_k<<<dim3(64, 64), tblk, 0, stream>>>(wo, woT, 4096, 4096);

    int totq = B_ * S_ * NH_ * (HD_ / 2);
    rope_k<<<(totq + 255) / 256, 256, 0, stream>>>(Q, NH_, 0.08838834764831845f);
    int totk = B_ * S_ * NKV_ * (HD_ / 2);
    rope_k<<<(totk + 255) / 256, 256, 0, stream>>>(Kb, NKV_, 1.0f);

    for (int b = 0; b < B_; ++b)
        transpose_k<<<dim3(16, 32), tblk, 0, stream>>>(
            Vb + (size_t)b * S_ * (NKV_ * HD_), Vt + (size_t)b * (NKV_ * HD_) * S_, S_, NKV_ * HD_);

    attn_k<<<dim3(S_ / 128, NH_, B_), 512, 0, stream>>>(Q, Kb, Vt, AO);

    gemm_bt<1><<<dim3(32, 32), 256, 0, stream>>>(AO, woT, out, 4096, 4096, 4096);
}